// Round 8
// baseline (194.718 us; speedup 1.0000x reference)
//
#include <hip/hip_runtime.h>
#include <hip/hip_bf16.h>

#define BB 32
#define NN 128
#define SD 128
#define ED 32
#define ID 256
#define BN (BB*NN)   // 4096
#define NI 4         // i-blocks per k2 workgroup
#define TT 2.885390082f   // 2*log2(e)

typedef __attribute__((ext_vector_type(8))) short sh8;
typedef __attribute__((ext_vector_type(4))) float f32x4;

__device__ __forceinline__ float ftanh(float x) {
    float e2 = exp2f(x * TT);
    return fmaf(-2.0f, __builtin_amdgcn_rcpf(e2 + 1.0f), 1.0f);
}

__device__ __forceinline__ ushort f2bf(float f) {
    unsigned u = __float_as_uint(f);
    return (ushort)((u + 0x7FFF + ((u >> 16) & 1)) >> 16);
}

// ---------------------------------------------------------------------------
// K1: node projections (f32, exact). 16 rows per block.
// which 0: Hgi2 = TT*(h@Wg1[0:128]+bg1)   1: Hgjt (MFMA-C frag tiles)
//       2: Hmi2 = TT*(h@Wm1[0:128]+bm1)   3: Hmjt (MFMA-C frag tiles)
//       4: (blocks 0..7) Bprep: bf16 B-fragments of We = W1[256:288,:]
// Hxjt layout: [(tile*256 + k)*16 + r], tile = b*8+s, r = row within stripe.
// grid (BN/16, 5), block 256
// ---------------------------------------------------------------------------
__global__ void k1_preproj(const float* __restrict__ h,
                           const float* __restrict__ Wg1, const float* __restrict__ bg1,
                           const float* __restrict__ Wm1, const float* __restrict__ bm1,
                           float* __restrict__ Hgi2, float* __restrict__ Hgjt,
                           float* __restrict__ Hmi2, float* __restrict__ Hmjt,
                           ushort* __restrict__ Bprep) {
    const int tile = blockIdx.x;
    const int which = blockIdx.y;
    const int t = threadIdx.x;
    if (which == 4) {   // weight prep: 32 tiles x 64 lanes
        const int gid = tile * 256 + t;
        if (gid >= 32 * 64) return;
        const int wt = gid >> 6;
        const int l = gid & 63;
        const int mat = wt >> 4;
        const int nt = wt & 15;
        const float* W = mat ? Wm1 : Wg1;
        const int colw = nt * 16 + (l & 15);
        const int kbase = (l >> 4) * 8;
        sh8 v;
        #pragma unroll
        for (int e = 0; e < 8; ++e)
            v[e] = (short)f2bf(W[(size_t)(2 * SD + kbase + e) * ID + colw]);
        *(sh8*)&Bprep[(size_t)wt * 512 + l * 8] = v;
        return;
    }
    __shared__ float hs[16][SD];
    const float* hrow = h + (size_t)tile * 16 * SD;
    for (int i = t; i < 16 * SD; i += 256) hs[i >> 7][i & 127] = hrow[i];
    __syncthreads();
    const float* W; const float* bias = nullptr; float* out;
    if (which == 0)      { W = Wg1;           bias = bg1; out = Hgi2; }
    else if (which == 1) { W = Wg1 + SD * ID;             out = Hgjt; }
    else if (which == 2) { W = Wm1;           bias = bm1; out = Hmi2; }
    else                 { W = Wm1 + SD * ID;             out = Hmjt; }
    const int k = t;
    float acc[16];
    const float b0 = bias ? bias[k] : 0.0f;
    #pragma unroll
    for (int r = 0; r < 16; ++r) acc[r] = b0;
    for (int c = 0; c < SD; ++c) {
        const float wv = W[c * ID + k];
        #pragma unroll
        for (int r = 0; r < 16; ++r) acc[r] = fmaf(hs[r][c], wv, acc[r]);
    }
    if (which & 1) {
        #pragma unroll
        for (int r = 0; r < 16; ++r) out[((size_t)tile * ID + k) * 16 + r] = acc[r];
    } else {
        #pragma unroll
        for (int r = 0; r < 16; ++r) out[(size_t)(tile * 16 + r) * ID + k] = acc[r] * TT;
    }
}

// ---------------------------------------------------------------------------
// K2: NI=4 i's of one b per block, 256 threads (4 waves, k-split 64/wave).
// E-proj via MFMA (K=32, bf16) with Hxjt frag tiles as the MFMA C operand
// (1 dwordx4/quadrant, double-buffered over s, amortized over NI=4 i's).
// Folded epilogues: exp2(fma(acc,TT,hgi2)); sum wg2/g algebraically hoisted.
// grid BN/NI, block 256
// ---------------------------------------------------------------------------
__global__ __launch_bounds__(256, 4) void k2_edges(
        const float* __restrict__ ef, const float* __restrict__ em,
        const ushort* __restrict__ Bprep,
        const float* __restrict__ Hgi2, const float* __restrict__ Hmi2,
        const float* __restrict__ Hgjt, const float* __restrict__ Hmjt,
        const float* __restrict__ Wg2, const float* __restrict__ bg2,
        float* __restrict__ T, float* __restrict__ gsum, float* __restrict__ deg) {
    const int bi0 = blockIdx.x * NI;
    const int b = bi0 >> 7;
    const int t = threadIdx.x;
    const int w = t >> 6;
    const int lane = t & 63;
    const int col = lane & 15;
    const int grp = lane >> 4;

    __shared__ __align__(16) ushort Elds[NI * 8 * 512];   // 32 KB
    __shared__ float glds[NI][NN];                        // 2 KB
    __shared__ float red[NI][2][2];

    // ---- zero glds; stage E (frag-ordered, conflict-free)
    {
        float* gl = &glds[0][0];
        gl[t] = 0.f;
        gl[t + 256] = 0.f;
    }
    #pragma unroll
    for (int i = 0; i < NI; ++i) {
        const float* efb = ef + (size_t)(bi0 + i) * NN * ED;
        #pragma unroll
        for (int it = 0; it < 2; ++it) {
            const int c = it * 256 + t;                    // chunk 0..511
            const int j = ((c >> 6) << 4) | (c & 15);
            const int kb = ((c >> 4) & 3) * 8;
            const float* p = efb + j * ED + kb;
            f32x4 a0 = *(const f32x4*)p;
            f32x4 a1 = *(const f32x4*)(p + 4);
            sh8 v;
            v[0] = (short)f2bf(a0[0]); v[1] = (short)f2bf(a0[1]);
            v[2] = (short)f2bf(a0[2]); v[3] = (short)f2bf(a0[3]);
            v[4] = (short)f2bf(a1[0]); v[5] = (short)f2bf(a1[1]);
            v[6] = (short)f2bf(a1[2]); v[7] = (short)f2bf(a1[3]);
            *(sh8*)&Elds[i * 4096 + c * 8] = v;
        }
    }
    __syncthreads();

    const int kcol = w * 64 + col;
    sh8 Bg[4], Bm[4];
    #pragma unroll
    for (int n = 0; n < 4; ++n) {
        Bg[n] = *(const sh8*)&Bprep[(size_t)(w * 4 + n) * 512 + lane * 8];
        Bm[n] = *(const sh8*)&Bprep[(size_t)(16 + w * 4 + n) * 512 + lane * 8];
    }
    // per-lane base into frag-tile array for this b: + (s*256 + kcol)*16 + grp*4
    const float* HgjL = Hgjt + (size_t)b * 8 * ID * 16 + (size_t)kcol * 16 + grp * 4;
    const float* HmjL = Hmjt + (size_t)b * 8 * ID * 16 + (size_t)kcol * 16 + grp * 4;

    // ================= gate pass
    {
        float hgiR[NI][4], m2wg2R[4];
        float wg2sum = 0.f;
        #pragma unroll
        for (int n = 0; n < 4; ++n) {
            const float wv = Wg2[kcol + n * 16];
            m2wg2R[n] = -2.0f * wv;
            wg2sum += wv;
        }
        #pragma unroll
        for (int i = 0; i < NI; ++i)
            #pragma unroll
            for (int n = 0; n < 4; ++n)
                hgiR[i][n] = Hgi2[(size_t)(bi0 + i) * ID + kcol + n * 16];
        f32x4 Cg[4], Cn[4];
        #pragma unroll
        for (int n = 0; n < 4; ++n) Cg[n] = *(const f32x4*)(HgjL + n * 256);
        for (int s = 0; s < 8; ++s) {
            if (s < 7) {
                const float* ps = HgjL + (s + 1) * (ID * 16);
                #pragma unroll
                for (int n = 0; n < 4; ++n) Cn[n] = *(const f32x4*)(ps + n * 256);
            }
            #pragma unroll
            for (int i = 0; i < NI; ++i) {
                sh8 Af = *(const sh8*)&Elds[i * 4096 + s * 512 + lane * 8];
                f32x4 acc[4];
                #pragma unroll
                for (int n = 0; n < 4; ++n)
                    acc[n] = __builtin_amdgcn_mfma_f32_16x16x32_bf16(
                        Af, Bg[n], Cg[n], 0, 0, 0);
                float p[4] = {wg2sum, wg2sum, wg2sum, wg2sum};
                #pragma unroll
                for (int n = 0; n < 4; ++n)
                    #pragma unroll
                    for (int r = 0; r < 4; ++r) {
                        const float e2 = exp2f(fmaf(acc[n][r], TT, hgiR[i][n]));
                        const float rc = __builtin_amdgcn_rcpf(e2 + 1.0f);
                        p[r] = fmaf(m2wg2R[n], rc, p[r]);
                    }
                #pragma unroll
                for (int m = 1; m < 16; m <<= 1)
                    #pragma unroll
                    for (int r = 0; r < 4; ++r) p[r] += __shfl_xor(p[r], m, 64);
                if (col == 0) {
                    #pragma unroll
                    for (int r = 0; r < 4; ++r)
                        atomicAdd(&glds[i][s * 16 + grp * 4 + r], p[r]);
                }
            }
            #pragma unroll
            for (int n = 0; n < 4; ++n) Cg[n] = Cn[n];
        }
    }
    __syncthreads();

    // ---- sigmoid + mask, gsum/deg reductions (NI*128 = 512 values)
    {
        const float bg2v = bg2[0];
        #pragma unroll
        for (int it = 0; it < NI / 2; ++it) {
            const int i = it * 2 + (t >> 7);
            const int j = t & 127;
            const float pre = glds[i][j] + bg2v;
            const float m = em[(size_t)(bi0 + i) * NN + j];
            const float g = m * __builtin_amdgcn_rcpf(
                                1.0f + exp2f(-1.442695041f * pre));
            glds[i][j] = g;
            float gsv = g, dv = m;
            #pragma unroll
            for (int mm = 1; mm < 64; mm <<= 1) {
                gsv += __shfl_xor(gsv, mm, 64);
                dv  += __shfl_xor(dv, mm, 64);
            }
            if (lane == 0) { red[it * 2 + (w >> 1)][w & 1][0] = gsv;
                             red[it * 2 + (w >> 1)][w & 1][1] = dv; }
        }
    }
    __syncthreads();
    if (t < NI) {
        gsum[bi0 + t] = red[t][0][0] + red[t][1][0];
        deg[bi0 + t]  = red[t][0][1] + red[t][1][1];
    }

    // ================= msg pass
    {
        float hmiR[NI][4];
        #pragma unroll
        for (int i = 0; i < NI; ++i)
            #pragma unroll
            for (int n = 0; n < 4; ++n)
                hmiR[i][n] = Hmi2[(size_t)(bi0 + i) * ID + kcol + n * 16];
        float ts[NI][4], GS[NI];
        #pragma unroll
        for (int i = 0; i < NI; ++i) {
            GS[i] = 0.f;
            #pragma unroll
            for (int n = 0; n < 4; ++n) ts[i][n] = 0.f;
        }
        f32x4 Cm[4], Cn[4];
        #pragma unroll
        for (int n = 0; n < 4; ++n) Cm[n] = *(const f32x4*)(HmjL + n * 256);
        for (int s = 0; s < 8; ++s) {
            if (s < 7) {
                const float* ps = HmjL + (s + 1) * (ID * 16);
                #pragma unroll
                for (int n = 0; n < 4; ++n) Cn[n] = *(const f32x4*)(ps + n * 256);
            }
            #pragma unroll
            for (int i = 0; i < NI; ++i) {
                sh8 Af = *(const sh8*)&Elds[i * 4096 + s * 512 + lane * 8];
                f32x4 acc[4];
                #pragma unroll
                for (int n = 0; n < 4; ++n)
                    acc[n] = __builtin_amdgcn_mfma_f32_16x16x32_bf16(
                        Af, Bm[n], Cm[n], 0, 0, 0);
                f32x4 gr = *(const f32x4*)&glds[i][s * 16 + grp * 4];
                GS[i] += (gr[0] + gr[1]) + (gr[2] + gr[3]);
                #pragma unroll
                for (int n = 0; n < 4; ++n)
                    #pragma unroll
                    for (int r = 0; r < 4; ++r) {
                        const float e2 = exp2f(fmaf(acc[n][r], TT, hmiR[i][n]));
                        const float rc = __builtin_amdgcn_rcpf(e2 + 1.0f);
                        ts[i][n] = fmaf(gr[r], rc, ts[i][n]);
                    }
            }
            #pragma unroll
            for (int n = 0; n < 4; ++n) Cm[n] = Cn[n];
        }
        #pragma unroll
        for (int i = 0; i < NI; ++i)
            #pragma unroll
            for (int n = 0; n < 4; ++n) {
                float v = fmaf(-2.0f, ts[i][n], GS[i]);   // sum g*tanh
                v += __shfl_xor(v, 16, 64);
                v += __shfl_xor(v, 32, 64);
                ts[i][n] = v;
            }
        if (lane < 16) {
            #pragma unroll
            for (int i = 0; i < NI; ++i)
                #pragma unroll
                for (int n = 0; n < 4; ++n)
                    T[(size_t)(bi0 + i) * ID + w * 64 + n * 16 + lane] = ts[i][n];
        }
    }
}

// ---------------------------------------------------------------------------
// K34: fused agg (T@Wm2) -> update MLP -> residual -> LayerNorm, 8 rows/block
// grid BN/8, block 256
// ---------------------------------------------------------------------------
__global__ void k34_update(const float* __restrict__ T, const float* __restrict__ gsum,
                           const float* __restrict__ deg, const float* __restrict__ h,
                           const float* __restrict__ Wm2, const float* __restrict__ bm2,
                           const float* __restrict__ Wu1, const float* __restrict__ bu1,
                           const float* __restrict__ Wu2, const float* __restrict__ bu2,
                           const float* __restrict__ lnw, const float* __restrict__ lnb,
                           float* __restrict__ out) {
    const int tile = blockIdx.x;
    const int row0 = tile * 8;
    __shared__ float Ts[8][ID];
    __shared__ float up[8][2 * SD + 1];
    __shared__ float u[8][ID];
    __shared__ float xs[8][SD];
    __shared__ float gss[8];
    const int t = threadIdx.x;
    const float* Tb = T + (size_t)row0 * ID;
    for (int i = t; i < 8 * ID; i += 256) Ts[i >> 8][i & 255] = Tb[i];
    for (int i = t; i < 8 * SD; i += 256) up[i >> 7][i & 127] = h[(size_t)row0 * SD + i];
    if (t < 8) {
        gss[t] = gsum[row0 + t];
        up[t][2 * SD] = deg[row0 + t] * (1.0f / 127.0f);
    }
    __syncthreads();
    {   // agg -> up[r][128+d]
        const int d = t & 127;
        const int r0 = (t >> 7) * 4;
        float acc[4] = {0.f, 0.f, 0.f, 0.f};
        for (int kk = 0; kk < ID; ++kk) {
            const float wv = Wm2[kk * SD + d];
            #pragma unroll
            for (int r = 0; r < 4; ++r) acc[r] = fmaf(Ts[r0 + r][kk], wv, acc[r]);
        }
        const float bmv = bm2[d];
        #pragma unroll
        for (int r = 0; r < 4; ++r) {
            const float g = gss[r0 + r];
            up[r0 + r][SD + d] = (acc[r] + g * bmv) *
                                 __builtin_amdgcn_rcpf(fmaxf(g, 1.0f));
        }
    }
    __syncthreads();
    {   // FC1 (257 -> 256) + tanh
        float acc[8];
        const float bk = bu1[t];
        #pragma unroll
        for (int r = 0; r < 8; ++r) acc[r] = bk;
        for (int c = 0; c < 2 * SD + 1; ++c) {
            const float wv = Wu1[c * ID + t];
            #pragma unroll
            for (int r = 0; r < 8; ++r) acc[r] = fmaf(up[r][c], wv, acc[r]);
        }
        #pragma unroll
        for (int r = 0; r < 8; ++r) u[r][t] = ftanh(acc[r]);
    }
    __syncthreads();
    {   // FC2 (256 -> 128) + tanh + residual
        const int d = t & 127;
        const int r0 = (t >> 7) * 4;
        float acc[4];
        const float bd = bu2[d];
        #pragma unroll
        for (int r = 0; r < 4; ++r) acc[r] = bd;
        for (int kk = 0; kk < ID; ++kk) {
            const float wv = Wu2[kk * SD + d];
            #pragma unroll
            for (int r = 0; r < 4; ++r) acc[r] = fmaf(u[r0 + r][kk], wv, acc[r]);
        }
        #pragma unroll
        for (int r = 0; r < 4; ++r) xs[r0 + r][d] = up[r0 + r][d] + ftanh(acc[r]);
    }
    __syncthreads();
    const int w = t >> 6, lane = t & 63;
    #pragma unroll
    for (int rr = 0; rr < 2; ++rr) {
        const int r = w * 2 + rr;
        const float v0 = xs[r][lane], v1 = xs[r][lane + 64];
        float s = v0 + v1;
        #pragma unroll
        for (int m = 1; m < 64; m <<= 1) s += __shfl_xor(s, m, 64);
        const float mu = s * (1.0f / SD);
        const float d0 = v0 - mu, d1 = v1 - mu;
        float q = d0 * d0 + d1 * d1;
        #pragma unroll
        for (int m = 1; m < 64; m <<= 1) q += __shfl_xor(q, m, 64);
        const float inv = rsqrtf(q * (1.0f / SD) + 1e-5f);
        out[(size_t)(row0 + r) * SD + lane] = d0 * inv * lnw[lane] + lnb[lane];
        out[(size_t)(row0 + r) * SD + lane + 64] = d1 * inv * lnw[lane + 64] + lnb[lane + 64];
    }
}

extern "C" void kernel_launch(void* const* d_in, const int* in_sizes, int n_in,
                              void* d_out, int out_size, void* d_ws, size_t ws_size,
                              hipStream_t stream) {
    const float* h   = (const float*)d_in[0];
    const float* ef  = (const float*)d_in[1];
    const float* em  = (const float*)d_in[2];
    const float* Wm1 = (const float*)d_in[3];
    const float* bm1 = (const float*)d_in[4];
    const float* Wm2 = (const float*)d_in[5];
    const float* bm2 = (const float*)d_in[6];
    const float* Wg1 = (const float*)d_in[7];
    const float* bg1 = (const float*)d_in[8];
    const float* Wg2 = (const float*)d_in[9];
    const float* bg2 = (const float*)d_in[10];
    const float* Wu1 = (const float*)d_in[11];
    const float* bu1 = (const float*)d_in[12];
    const float* Wu2 = (const float*)d_in[13];
    const float* bu2 = (const float*)d_in[14];
    const float* lnw = (const float*)d_in[15];
    const float* lnb = (const float*)d_in[16];

    float* ws = (float*)d_ws;
    float* Hgi2  = ws;
    float* Hgjt  = Hgi2 + (size_t)BN * ID;
    float* Hmi2  = Hgjt + (size_t)BN * ID;
    float* Hmjt  = Hmi2 + (size_t)BN * ID;
    float* T     = Hmjt + (size_t)BN * ID;
    float* gsumv = T + (size_t)BN * ID;
    float* degv  = gsumv + BN;
    ushort* Bprep = (ushort*)(degv + BN);
    float* outp = (float*)d_out;

    k1_preproj<<<dim3(BN / 16, 5), 256, 0, stream>>>(h, Wg1, bg1, Wm1, bm1,
                                                     Hgi2, Hgjt, Hmi2, Hmjt, Bprep);
    k2_edges<<<BN / NI, 256, 0, stream>>>(ef, em, Bprep, Hgi2, Hmi2, Hgjt, Hmjt,
                                          Wg2, bg2, T, gsumv, degv);
    k34_update<<<BN / 8, 256, 0, stream>>>(T, gsumv, degv, h, Wm2, bm2,
                                           Wu1, bu1, Wu2, bu2, lnw, lnb, outp);
}

// Round 9
// 181.048 us; speedup vs baseline: 1.0755x; 1.0755x over previous
//
#include <hip/hip_runtime.h>
#include <hip/hip_bf16.h>

#define BB 32
#define NN 128
#define SD 128
#define ED 32
#define ID 256
#define BN (BB*NN)   // 4096
#define NI 4         // i-blocks per k2 workgroup

typedef __attribute__((ext_vector_type(8))) short sh8;
typedef __attribute__((ext_vector_type(4))) float f32x4;

__device__ __forceinline__ float ftanh(float x) {
    float e2 = __expf(2.0f * x);
    return 1.0f - 2.0f * __builtin_amdgcn_rcpf(e2 + 1.0f);
}

__device__ __forceinline__ ushort f2bf(float f) {
    unsigned u = __float_as_uint(f);
    return (ushort)((u + 0x7FFF + ((u >> 16) & 1)) >> 16);
}

// ---------------------------------------------------------------------------
// k_prep: frag-ordered bf16 B-tiles of W1 (both matrices, all row-ranges).
// tiles 0..255:  [tgt(4)][kt(4)][nt(16)], tgt: 0=Wg1[0:128] 1=Wg1[128:256]
//                2=Wm1[0:128] 3=Wm1[128:256], rows kt*32..+32
// tiles 256..287: We = W1[256:288]  (256..271 gate, 272..287 msg)
// lane l of tile: B[k=(l>>4)*8+e][col = nt*16 + (l&15)]
// grid 288, block 64
// ---------------------------------------------------------------------------
__global__ void k_prep(const float* __restrict__ Wg1, const float* __restrict__ Wm1,
                       ushort* __restrict__ Bprep) {
    const int tt = blockIdx.x;
    const int l = threadIdx.x;
    const float* W;
    int rowbase, nt;
    if (tt < 256) {
        const int tgt = tt >> 6;
        const int kt = (tt >> 4) & 3;
        nt = tt & 15;
        W = (tgt >= 2) ? Wm1 : Wg1;
        rowbase = (tgt & 1) * 128 + kt * 32;
    } else {
        const int wt = tt - 256;
        W = (wt >> 4) ? Wm1 : Wg1;
        rowbase = 2 * SD;
        nt = wt & 15;
    }
    const int colw = nt * 16 + (l & 15);
    const int kb = rowbase + (l >> 4) * 8;
    sh8 v;
    #pragma unroll
    for (int e = 0; e < 8; ++e)
        v[e] = (short)f2bf(W[(size_t)(kb + e) * ID + colw]);
    *(sh8*)&Bprep[(size_t)tt * 512 + l * 8] = v;
}

// ---------------------------------------------------------------------------
// K1 (MFMA): one 16-row stripe per block. Stage h as bf16 A-frags (validated
// staging pattern), then 4 targets x 16 MFMA (K=128).
//  tgt 0: Hgi = h@Wg1[0:128]+bg1 (normal layout)   1: Hgjt (frag tiles)
//  tgt 2: Hmi = h@Wm1[0:128]+bm1 (normal layout)   3: Hmjt (frag tiles)
// Hxjt layout: [(gs*256 + k)*16 + r], gs = stripe = blockIdx.x.
// grid BN/16, block 256
// ---------------------------------------------------------------------------
__global__ __launch_bounds__(256) void k1_mfma(
        const float* __restrict__ h,
        const float* __restrict__ bg1, const float* __restrict__ bm1,
        const ushort* __restrict__ Bprep,
        float* __restrict__ Hgi, float* __restrict__ Hgjt,
        float* __restrict__ Hmi, float* __restrict__ Hmjt) {
    const int blk = blockIdx.x;          // stripe: rows blk*16 .. +16
    const int t = threadIdx.x;
    const int w = t >> 6;
    const int lane = t & 63;
    const int col = lane & 15;
    const int grp = lane >> 4;
    __shared__ __align__(16) ushort Alds[4 * 512];   // 4 k-tiles

    {   // stage h rows -> bf16 frag order (1 chunk / thread)
        const int c = t;
        const int kt = c >> 6, l = c & 63;
        const int row = l & 15;
        const int kb = kt * 32 + (l >> 4) * 8;
        const float* p = h + (size_t)(blk * 16 + row) * SD + kb;
        f32x4 a0 = *(const f32x4*)p;
        f32x4 a1 = *(const f32x4*)(p + 4);
        sh8 v;
        v[0] = (short)f2bf(a0[0]); v[1] = (short)f2bf(a0[1]);
        v[2] = (short)f2bf(a0[2]); v[3] = (short)f2bf(a0[3]);
        v[4] = (short)f2bf(a1[0]); v[5] = (short)f2bf(a1[1]);
        v[6] = (short)f2bf(a1[2]); v[7] = (short)f2bf(a1[3]);
        *(sh8*)&Alds[c * 8] = v;
    }
    __syncthreads();

    const int kcol = w * 64 + col;
    sh8 Af[4];
    #pragma unroll
    for (int kt = 0; kt < 4; ++kt)
        Af[kt] = *(const sh8*)&Alds[kt * 512 + lane * 8];

    #pragma unroll
    for (int tgt = 0; tgt < 4; ++tgt) {
        f32x4 acc[4];
        #pragma unroll
        for (int n = 0; n < 4; ++n) acc[n] = (f32x4){0.f, 0.f, 0.f, 0.f};
        #pragma unroll
        for (int kt = 0; kt < 4; ++kt)
            #pragma unroll
            for (int n = 0; n < 4; ++n) {
                sh8 Bf = *(const sh8*)&Bprep[
                    (size_t)(tgt * 64 + kt * 16 + w * 4 + n) * 512 + lane * 8];
                acc[n] = __builtin_amdgcn_mfma_f32_16x16x32_bf16(
                    Af[kt], Bf, acc[n], 0, 0, 0);
            }
        if (tgt & 1) {          // frag-tile store (gj / mj)
            float* out = (tgt == 1) ? Hgjt : Hmjt;
            #pragma unroll
            for (int n = 0; n < 4; ++n)
                *(f32x4*)&out[((size_t)blk * ID + kcol + n * 16) * 16 + grp * 4] =
                    acc[n];
        } else {                // normal layout + bias (gi / mi)
            const float* bias = (tgt == 0) ? bg1 : bm1;
            float* out = (tgt == 0) ? Hgi : Hmi;
            #pragma unroll
            for (int n = 0; n < 4; ++n) {
                const float bv = bias[kcol + n * 16];
                #pragma unroll
                for (int r = 0; r < 4; ++r)
                    out[(size_t)(blk * 16 + grp * 4 + r) * ID + kcol + n * 16] =
                        acc[n][r] + bv;
            }
        }
    }
}

// ---------------------------------------------------------------------------
// K2: NI=4 i's of one b per block (R5-measured best form, verbatim).
// E-proj via MFMA (K=32, bf16) with Hxjt frag tiles as the MFMA C operand.
// grid BN/NI, block 256
// ---------------------------------------------------------------------------
__global__ __launch_bounds__(256, 4) void k2_edges(
        const float* __restrict__ ef, const float* __restrict__ em,
        const ushort* __restrict__ Bprep,
        const float* __restrict__ Hgi, const float* __restrict__ Hmi,
        const float* __restrict__ Hgjt, const float* __restrict__ Hmjt,
        const float* __restrict__ Wg2, const float* __restrict__ bg2,
        float* __restrict__ T, float* __restrict__ gsum, float* __restrict__ deg) {
    const int bi0 = blockIdx.x * NI;
    const int b = bi0 >> 7;
    const int t = threadIdx.x;
    const int w = t >> 6;
    const int lane = t & 63;
    const int col = lane & 15;
    const int grp = lane >> 4;

    __shared__ __align__(16) ushort Elds[NI * 8 * 512];   // 32 KB
    __shared__ float glds[NI][NN];                        // 2 KB
    __shared__ float red[2][4][2];

    {
        float* gl = &glds[0][0];
        gl[t] = 0.f;
        gl[t + 256] = 0.f;
    }
    #pragma unroll
    for (int i = 0; i < NI; ++i) {
        const float* efb = ef + (size_t)(bi0 + i) * NN * ED;
        #pragma unroll
        for (int it = 0; it < 2; ++it) {
            const int c = it * 256 + t;                    // chunk 0..511
            const int j = ((c >> 6) << 4) | (c & 15);
            const int kb = ((c >> 4) & 3) * 8;
            const float* p = efb + j * ED + kb;
            f32x4 a0 = *(const f32x4*)p;
            f32x4 a1 = *(const f32x4*)(p + 4);
            sh8 v;
            v[0] = (short)f2bf(a0[0]); v[1] = (short)f2bf(a0[1]);
            v[2] = (short)f2bf(a0[2]); v[3] = (short)f2bf(a0[3]);
            v[4] = (short)f2bf(a1[0]); v[5] = (short)f2bf(a1[1]);
            v[6] = (short)f2bf(a1[2]); v[7] = (short)f2bf(a1[3]);
            *(sh8*)&Elds[i * 4096 + c * 8] = v;
        }
    }
    __syncthreads();

    const int kcol = w * 64 + col;
    sh8 Bg[4], Bm[4];
    #pragma unroll
    for (int n = 0; n < 4; ++n) {
        Bg[n] = *(const sh8*)&Bprep[(size_t)(256 + w * 4 + n) * 512 + lane * 8];
        Bm[n] = *(const sh8*)&Bprep[(size_t)(272 + w * 4 + n) * 512 + lane * 8];
    }
    const float* HgjL = Hgjt + (size_t)b * 8 * ID * 16 + (size_t)kcol * 16 + grp * 4;
    const float* HmjL = Hmjt + (size_t)b * 8 * ID * 16 + (size_t)kcol * 16 + grp * 4;

    // ================= gate pass
    {
        float hgiR[NI][4], wg2R[4];
        #pragma unroll
        for (int n = 0; n < 4; ++n) wg2R[n] = Wg2[kcol + n * 16];
        #pragma unroll
        for (int i = 0; i < NI; ++i)
            #pragma unroll
            for (int n = 0; n < 4; ++n)
                hgiR[i][n] = Hgi[(size_t)(bi0 + i) * ID + kcol + n * 16];
        f32x4 Cg[4], Cn[4];
        #pragma unroll
        for (int n = 0; n < 4; ++n) Cg[n] = *(const f32x4*)(HgjL + n * 256);
        for (int s = 0; s < 8; ++s) {
            if (s < 7) {
                const float* ps = HgjL + (s + 1) * (ID * 16);
                #pragma unroll
                for (int n = 0; n < 4; ++n) Cn[n] = *(const f32x4*)(ps + n * 256);
            }
            #pragma unroll
            for (int i = 0; i < NI; ++i) {
                sh8 Af = *(const sh8*)&Elds[i * 4096 + s * 512 + lane * 8];
                f32x4 acc[4];
                #pragma unroll
                for (int n = 0; n < 4; ++n)
                    acc[n] = __builtin_amdgcn_mfma_f32_16x16x32_bf16(
                        Af, Bg[n], Cg[n], 0, 0, 0);
                float p[4] = {0.f, 0.f, 0.f, 0.f};
                #pragma unroll
                for (int n = 0; n < 4; ++n)
                    #pragma unroll
                    for (int r = 0; r < 4; ++r)
                        p[r] = fmaf(ftanh(acc[n][r] + hgiR[i][n]), wg2R[n], p[r]);
                #pragma unroll
                for (int m = 1; m < 16; m <<= 1)
                    #pragma unroll
                    for (int r = 0; r < 4; ++r) p[r] += __shfl_xor(p[r], m, 64);
                if (col == 0) {
                    #pragma unroll
                    for (int r = 0; r < 4; ++r)
                        atomicAdd(&glds[i][s * 16 + grp * 4 + r], p[r]);
                }
            }
            #pragma unroll
            for (int n = 0; n < 4; ++n) Cg[n] = Cn[n];
        }
    }
    __syncthreads();

    // ---- sigmoid + mask, gsum/deg reductions
    {
        const float bg2v = bg2[0];
        #pragma unroll
        for (int it = 0; it < NI / 2; ++it) {
            const int i = it * 2 + (t >> 7);
            const int j = t & 127;
            const float pre = glds[i][j] + bg2v;
            const float m = em[(size_t)(bi0 + i) * NN + j];
            const float g = m * __builtin_amdgcn_rcpf(1.0f + __expf(-pre));
            glds[i][j] = g;
            float gsv = g, dv = m;
            #pragma unroll
            for (int mm = 1; mm < 64; mm <<= 1) {
                gsv += __shfl_xor(gsv, mm, 64);
                dv  += __shfl_xor(dv, mm, 64);
            }
            if (lane == 0) { red[it][w][0] = gsv; red[it][w][1] = dv; }
        }
    }
    __syncthreads();
    if (t < NI) {
        const int it = t >> 1, w0 = (t & 1) * 2;
        gsum[bi0 + t] = red[it][w0][0] + red[it][w0 + 1][0];
        deg[bi0 + t]  = red[it][w0][1] + red[it][w0 + 1][1];
    }

    // ================= msg pass
    {
        float hmiR[NI][4];
        #pragma unroll
        for (int i = 0; i < NI; ++i)
            #pragma unroll
            for (int n = 0; n < 4; ++n)
                hmiR[i][n] = Hmi[(size_t)(bi0 + i) * ID + kcol + n * 16];
        float ts[NI][4];
        #pragma unroll
        for (int i = 0; i < NI; ++i)
            #pragma unroll
            for (int n = 0; n < 4; ++n) ts[i][n] = 0.f;
        f32x4 Cm[4], Cn[4];
        #pragma unroll
        for (int n = 0; n < 4; ++n) Cm[n] = *(const f32x4*)(HmjL + n * 256);
        for (int s = 0; s < 8; ++s) {
            if (s < 7) {
                const float* ps = HmjL + (s + 1) * (ID * 16);
                #pragma unroll
                for (int n = 0; n < 4; ++n) Cn[n] = *(const f32x4*)(ps + n * 256);
            }
            #pragma unroll
            for (int i = 0; i < NI; ++i) {
                sh8 Af = *(const sh8*)&Elds[i * 4096 + s * 512 + lane * 8];
                f32x4 acc[4];
                #pragma unroll
                for (int n = 0; n < 4; ++n)
                    acc[n] = __builtin_amdgcn_mfma_f32_16x16x32_bf16(
                        Af, Bm[n], Cm[n], 0, 0, 0);
                f32x4 gr = *(const f32x4*)&glds[i][s * 16 + grp * 4];
                #pragma unroll
                for (int n = 0; n < 4; ++n)
                    #pragma unroll
                    for (int r = 0; r < 4; ++r)
                        ts[i][n] = fmaf(gr[r], ftanh(acc[n][r] + hmiR[i][n]),
                                        ts[i][n]);
            }
            #pragma unroll
            for (int n = 0; n < 4; ++n) Cm[n] = Cn[n];
        }
        #pragma unroll
        for (int i = 0; i < NI; ++i)
            #pragma unroll
            for (int n = 0; n < 4; ++n) {
                ts[i][n] += __shfl_xor(ts[i][n], 16, 64);
                ts[i][n] += __shfl_xor(ts[i][n], 32, 64);
            }
        if (lane < 16) {
            #pragma unroll
            for (int i = 0; i < NI; ++i)
                #pragma unroll
                for (int n = 0; n < 4; ++n)
                    T[(size_t)(bi0 + i) * ID + kcol - col + n * 16 + lane] = ts[i][n];
        }
    }
}

// ---------------------------------------------------------------------------
// K34: fused agg (T@Wm2) -> update MLP -> residual -> LayerNorm, 8 rows/block
// grid BN/8, block 256
// ---------------------------------------------------------------------------
__global__ void k34_update(const float* __restrict__ T, const float* __restrict__ gsum,
                           const float* __restrict__ deg, const float* __restrict__ h,
                           const float* __restrict__ Wm2, const float* __restrict__ bm2,
                           const float* __restrict__ Wu1, const float* __restrict__ bu1,
                           const float* __restrict__ Wu2, const float* __restrict__ bu2,
                           const float* __restrict__ lnw, const float* __restrict__ lnb,
                           float* __restrict__ out) {
    const int tile = blockIdx.x;
    const int row0 = tile * 8;
    __shared__ float Ts[8][ID];
    __shared__ float up[8][2 * SD + 1];
    __shared__ float u[8][ID];
    __shared__ float xs[8][SD];
    __shared__ float gss[8];
    const int t = threadIdx.x;
    const float* Tb = T + (size_t)row0 * ID;
    for (int i = t; i < 8 * ID; i += 256) Ts[i >> 8][i & 255] = Tb[i];
    for (int i = t; i < 8 * SD; i += 256) up[i >> 7][i & 127] = h[(size_t)row0 * SD + i];
    if (t < 8) {
        gss[t] = gsum[row0 + t];
        up[t][2 * SD] = deg[row0 + t] * (1.0f / 127.0f);
    }
    __syncthreads();
    {   // agg -> up[r][128+d]
        const int d = t & 127;
        const int r0 = (t >> 7) * 4;
        float acc[4] = {0.f, 0.f, 0.f, 0.f};
        for (int kk = 0; kk < ID; ++kk) {
            const float wv = Wm2[kk * SD + d];
            #pragma unroll
            for (int r = 0; r < 4; ++r) acc[r] = fmaf(Ts[r0 + r][kk], wv, acc[r]);
        }
        const float bmv = bm2[d];
        #pragma unroll
        for (int r = 0; r < 4; ++r) {
            const float g = gss[r0 + r];
            up[r0 + r][SD + d] = (acc[r] + g * bmv) *
                                 __builtin_amdgcn_rcpf(fmaxf(g, 1.0f));
        }
    }
    __syncthreads();
    {   // FC1 (257 -> 256) + tanh
        float acc[8];
        const float bk = bu1[t];
        #pragma unroll
        for (int r = 0; r < 8; ++r) acc[r] = bk;
        for (int c = 0; c < 2 * SD + 1; ++c) {
            const float wv = Wu1[c * ID + t];
            #pragma unroll
            for (int r = 0; r < 8; ++r) acc[r] = fmaf(up[r][c], wv, acc[r]);
        }
        #pragma unroll
        for (int r = 0; r < 8; ++r) u[r][t] = ftanh(acc[r]);
    }
    __syncthreads();
    {   // FC2 (256 -> 128) + tanh + residual
        const int d = t & 127;
        const int r0 = (t >> 7) * 4;
        float acc[4];
        const float bd = bu2[d];
        #pragma unroll
        for (int r = 0; r < 4; ++r) acc[r] = bd;
        for (int kk = 0; kk < ID; ++kk) {
            const float wv = Wu2[kk * SD + d];
            #pragma unroll
            for (int r = 0; r < 4; ++r) acc[r] = fmaf(u[r0 + r][kk], wv, acc[r]);
        }
        #pragma unroll
        for (int r = 0; r < 4; ++r) xs[r0 + r][d] = up[r0 + r][d] + ftanh(acc[r]);
    }
    __syncthreads();
    const int w = t >> 6, lane = t & 63;
    #pragma unroll
    for (int rr = 0; rr < 2; ++rr) {
        const int r = w * 2 + rr;
        const float v0 = xs[r][lane], v1 = xs[r][lane + 64];
        float s = v0 + v1;
        #pragma unroll
        for (int m = 1; m < 64; m <<= 1) s += __shfl_xor(s, m, 64);
        const float mu = s * (1.0f / SD);
        const float d0 = v0 - mu, d1 = v1 - mu;
        float q = d0 * d0 + d1 * d1;
        #pragma unroll
        for (int m = 1; m < 64; m <<= 1) q += __shfl_xor(q, m, 64);
        const float inv = rsqrtf(q * (1.0f / SD) + 1e-5f);
        out[(size_t)(row0 + r) * SD + lane] = d0 * inv * lnw[lane] + lnb[lane];
        out[(size_t)(row0 + r) * SD + lane + 64] = d1 * inv * lnw[lane + 64] + lnb[lane + 64];
    }
}

extern "C" void kernel_launch(void* const* d_in, const int* in_sizes, int n_in,
                              void* d_out, int out_size, void* d_ws, size_t ws_size,
                              hipStream_t stream) {
    const float* h   = (const float*)d_in[0];
    const float* ef  = (const float*)d_in[1];
    const float* em  = (const float*)d_in[2];
    const float* Wm1 = (const float*)d_in[3];
    const float* bm1 = (const float*)d_in[4];
    const float* Wm2 = (const float*)d_in[5];
    const float* bm2 = (const float*)d_in[6];
    const float* Wg1 = (const float*)d_in[7];
    const float* bg1 = (const float*)d_in[8];
    const float* Wg2 = (const float*)d_in[9];
    const float* bg2 = (const float*)d_in[10];
    const float* Wu1 = (const float*)d_in[11];
    const float* bu1 = (const float*)d_in[12];
    const float* Wu2 = (const float*)d_in[13];
    const float* bu2 = (const float*)d_in[14];
    const float* lnw = (const float*)d_in[15];
    const float* lnb = (const float*)d_in[16];

    float* ws = (float*)d_ws;
    float* Hgi   = ws;
    float* Hgjt  = Hgi + (size_t)BN * ID;
    float* Hmi   = Hgjt + (size_t)BN * ID;
    float* Hmjt  = Hmi + (size_t)BN * ID;
    float* T     = Hmjt + (size_t)BN * ID;
    float* gsumv = T + (size_t)BN * ID;
    float* degv  = gsumv + BN;
    ushort* Bprep = (ushort*)(degv + BN);
    float* outp = (float*)d_out;

    k_prep<<<288, 64, 0, stream>>>(Wg1, Wm1, Bprep);
    k1_mfma<<<BN / 16, 256, 0, stream>>>(h, bg1, bm1, Bprep,
                                         Hgi, Hgjt, Hmi, Hmjt);
    k2_edges<<<BN / NI, 256, 0, stream>>>(ef, em, Bprep, Hgi, Hmi, Hgjt, Hmjt,
                                          Wg2, bg2, T, gsumv, degv);
    k34_update<<<BN / 8, 256, 0, stream>>>(T, gsumv, degv, h, Wm2, bm2,
                                           Wu1, bu1, Wu2, bu2, lnw, lnb, outp);
}

// Round 10
// 141.142 us; speedup vs baseline: 1.3796x; 1.2827x over previous
//
#include <hip/hip_runtime.h>
#include <hip/hip_bf16.h>

#define BB 32
#define NN 128
#define SD 128
#define ED 32
#define ID 256
#define BN (BB*NN)   // 4096
#define NI 4         // i-blocks per k2 workgroup

typedef __attribute__((ext_vector_type(8))) short sh8;
typedef __attribute__((ext_vector_type(4))) float f32x4;

__device__ __forceinline__ float ftanh(float x) {
    float e2 = __expf(2.0f * x);
    return 1.0f - 2.0f * __builtin_amdgcn_rcpf(e2 + 1.0f);
}

__device__ __forceinline__ ushort f2bf(float f) {
    unsigned u = __float_as_uint(f);
    return (ushort)((u + 0x7FFF + ((u >> 16) & 1)) >> 16);
}

// ---------------------------------------------------------------------------
// k_prep: frag-ordered bf16 B-tiles of W1 (both matrices, all row-ranges).
// tiles 0..255:  [tgt(4)][kt(4)][nt(16)]; tiles 256..287: We rows 256..288.
// grid 288, block 64
// ---------------------------------------------------------------------------
__global__ void k_prep(const float* __restrict__ Wg1, const float* __restrict__ Wm1,
                       ushort* __restrict__ Bprep) {
    const int tt = blockIdx.x;
    const int l = threadIdx.x;
    const float* W;
    int rowbase, nt;
    if (tt < 256) {
        const int tgt = tt >> 6;
        const int kt = (tt >> 4) & 3;
        nt = tt & 15;
        W = (tgt >= 2) ? Wm1 : Wg1;
        rowbase = (tgt & 1) * 128 + kt * 32;
    } else {
        const int wt = tt - 256;
        W = (wt >> 4) ? Wm1 : Wg1;
        rowbase = 2 * SD;
        nt = wt & 15;
    }
    const int colw = nt * 16 + (l & 15);
    const int kb = rowbase + (l >> 4) * 8;
    sh8 v;
    #pragma unroll
    for (int e = 0; e < 8; ++e)
        v[e] = (short)f2bf(W[(size_t)(kb + e) * ID + colw]);
    *(sh8*)&Bprep[(size_t)tt * 512 + l * 8] = v;
}

// ---------------------------------------------------------------------------
// K1 (MFMA): one 16-row stripe x one target per block (grid.y = tgt).
//  tgt 0: Hgi = h@Wg1[0:128]+bg1 (normal)   1: Hgjt (frag tiles)
//  tgt 2: Hmi = h@Wm1[0:128]+bm1 (normal)   3: Hmjt (frag tiles)
// grid (BN/16, 4), block 256
// ---------------------------------------------------------------------------
__global__ __launch_bounds__(256) void k1_mfma(
        const float* __restrict__ h,
        const float* __restrict__ bg1, const float* __restrict__ bm1,
        const ushort* __restrict__ Bprep,
        float* __restrict__ Hgi, float* __restrict__ Hgjt,
        float* __restrict__ Hmi, float* __restrict__ Hmjt) {
    const int blk = blockIdx.x;
    const int tgt = blockIdx.y;
    const int t = threadIdx.x;
    const int w = t >> 6;
    const int lane = t & 63;
    const int col = lane & 15;
    const int grp = lane >> 4;
    __shared__ __align__(16) ushort Alds[4 * 512];

    {   // stage h rows -> bf16 frag order
        const int c = t;
        const int kt = c >> 6, l = c & 63;
        const int row = l & 15;
        const int kb = kt * 32 + (l >> 4) * 8;
        const float* p = h + (size_t)(blk * 16 + row) * SD + kb;
        f32x4 a0 = *(const f32x4*)p;
        f32x4 a1 = *(const f32x4*)(p + 4);
        sh8 v;
        v[0] = (short)f2bf(a0[0]); v[1] = (short)f2bf(a0[1]);
        v[2] = (short)f2bf(a0[2]); v[3] = (short)f2bf(a0[3]);
        v[4] = (short)f2bf(a1[0]); v[5] = (short)f2bf(a1[1]);
        v[6] = (short)f2bf(a1[2]); v[7] = (short)f2bf(a1[3]);
        *(sh8*)&Alds[c * 8] = v;
    }
    __syncthreads();

    const int kcol = w * 64 + col;
    sh8 Af[4];
    #pragma unroll
    for (int kt = 0; kt < 4; ++kt)
        Af[kt] = *(const sh8*)&Alds[kt * 512 + lane * 8];

    f32x4 acc[4];
    #pragma unroll
    for (int n = 0; n < 4; ++n) acc[n] = (f32x4){0.f, 0.f, 0.f, 0.f};
    #pragma unroll
    for (int kt = 0; kt < 4; ++kt)
        #pragma unroll
        for (int n = 0; n < 4; ++n) {
            sh8 Bf = *(const sh8*)&Bprep[
                (size_t)(tgt * 64 + kt * 16 + w * 4 + n) * 512 + lane * 8];
            acc[n] = __builtin_amdgcn_mfma_f32_16x16x32_bf16(
                Af[kt], Bf, acc[n], 0, 0, 0);
        }
    if (tgt & 1) {          // frag-tile store (gj / mj)
        float* out = (tgt == 1) ? Hgjt : Hmjt;
        #pragma unroll
        for (int n = 0; n < 4; ++n)
            *(f32x4*)&out[((size_t)blk * ID + kcol + n * 16) * 16 + grp * 4] = acc[n];
    } else {                // normal layout + bias (gi / mi)
        const float* bias = (tgt == 0) ? bg1 : bm1;
        float* out = (tgt == 0) ? Hgi : Hmi;
        #pragma unroll
        for (int n = 0; n < 4; ++n) {
            const float bv = bias[kcol + n * 16];
            #pragma unroll
            for (int r = 0; r < 4; ++r)
                out[(size_t)(blk * 16 + grp * 4 + r) * ID + kcol + n * 16] =
                    acc[n][r] + bv;
        }
    }
}

// ---------------------------------------------------------------------------
// K2 fused: edge passes (R5-measured best form) + in-block k34 tail
// (agg -> FC1 -> FC2 -> residual -> LayerNorm) for the block's NI=4 rows.
// Tail reuses Elds as f32 scratch (14.4 KB of 32 KB). grid BN/NI, block 256
// ---------------------------------------------------------------------------
__global__ __launch_bounds__(256, 4) void k2_fused(
        const float* __restrict__ ef, const float* __restrict__ em,
        const ushort* __restrict__ Bprep,
        const float* __restrict__ Hgi, const float* __restrict__ Hmi,
        const float* __restrict__ Hgjt, const float* __restrict__ Hmjt,
        const float* __restrict__ Wg2, const float* __restrict__ bg2,
        const float* __restrict__ h,
        const float* __restrict__ Wm2, const float* __restrict__ bm2,
        const float* __restrict__ Wu1, const float* __restrict__ bu1,
        const float* __restrict__ Wu2, const float* __restrict__ bu2,
        const float* __restrict__ lnw, const float* __restrict__ lnb,
        float* __restrict__ out) {
    const int bi0 = blockIdx.x * NI;
    const int b = bi0 >> 7;
    const int t = threadIdx.x;
    const int w = t >> 6;
    const int lane = t & 63;
    const int col = lane & 15;
    const int grp = lane >> 4;

    __shared__ __align__(16) ushort Elds[NI * 8 * 512];   // 32 KB
    __shared__ float glds[NI][NN];                        // 2 KB
    __shared__ float red[2][4][2];
    __shared__ float gsumL[NI], degL[NI];

    {
        float* gl = &glds[0][0];
        gl[t] = 0.f;
        gl[t + 256] = 0.f;
    }
    #pragma unroll
    for (int i = 0; i < NI; ++i) {
        const float* efb = ef + (size_t)(bi0 + i) * NN * ED;
        #pragma unroll
        for (int it = 0; it < 2; ++it) {
            const int c = it * 256 + t;                    // chunk 0..511
            const int j = ((c >> 6) << 4) | (c & 15);
            const int kb = ((c >> 4) & 3) * 8;
            const float* p = efb + j * ED + kb;
            f32x4 a0 = *(const f32x4*)p;
            f32x4 a1 = *(const f32x4*)(p + 4);
            sh8 v;
            v[0] = (short)f2bf(a0[0]); v[1] = (short)f2bf(a0[1]);
            v[2] = (short)f2bf(a0[2]); v[3] = (short)f2bf(a0[3]);
            v[4] = (short)f2bf(a1[0]); v[5] = (short)f2bf(a1[1]);
            v[6] = (short)f2bf(a1[2]); v[7] = (short)f2bf(a1[3]);
            *(sh8*)&Elds[i * 4096 + c * 8] = v;
        }
    }
    __syncthreads();

    const int kcol = w * 64 + col;
    sh8 Bg[4], Bm[4];
    #pragma unroll
    for (int n = 0; n < 4; ++n) {
        Bg[n] = *(const sh8*)&Bprep[(size_t)(256 + w * 4 + n) * 512 + lane * 8];
        Bm[n] = *(const sh8*)&Bprep[(size_t)(272 + w * 4 + n) * 512 + lane * 8];
    }
    const float* HgjL = Hgjt + (size_t)b * 8 * ID * 16 + (size_t)kcol * 16 + grp * 4;
    const float* HmjL = Hmjt + (size_t)b * 8 * ID * 16 + (size_t)kcol * 16 + grp * 4;

    // ================= gate pass
    {
        float hgiR[NI][4], wg2R[4];
        #pragma unroll
        for (int n = 0; n < 4; ++n) wg2R[n] = Wg2[kcol + n * 16];
        #pragma unroll
        for (int i = 0; i < NI; ++i)
            #pragma unroll
            for (int n = 0; n < 4; ++n)
                hgiR[i][n] = Hgi[(size_t)(bi0 + i) * ID + kcol + n * 16];
        f32x4 Cg[4], Cn[4];
        #pragma unroll
        for (int n = 0; n < 4; ++n) Cg[n] = *(const f32x4*)(HgjL + n * 256);
        for (int s = 0; s < 8; ++s) {
            if (s < 7) {
                const float* ps = HgjL + (s + 1) * (ID * 16);
                #pragma unroll
                for (int n = 0; n < 4; ++n) Cn[n] = *(const f32x4*)(ps + n * 256);
            }
            #pragma unroll
            for (int i = 0; i < NI; ++i) {
                sh8 Af = *(const sh8*)&Elds[i * 4096 + s * 512 + lane * 8];
                f32x4 acc[4];
                #pragma unroll
                for (int n = 0; n < 4; ++n)
                    acc[n] = __builtin_amdgcn_mfma_f32_16x16x32_bf16(
                        Af, Bg[n], Cg[n], 0, 0, 0);
                float p[4] = {0.f, 0.f, 0.f, 0.f};
                #pragma unroll
                for (int n = 0; n < 4; ++n)
                    #pragma unroll
                    for (int r = 0; r < 4; ++r)
                        p[r] = fmaf(ftanh(acc[n][r] + hgiR[i][n]), wg2R[n], p[r]);
                #pragma unroll
                for (int m = 1; m < 16; m <<= 1)
                    #pragma unroll
                    for (int r = 0; r < 4; ++r) p[r] += __shfl_xor(p[r], m, 64);
                if (col == 0) {
                    #pragma unroll
                    for (int r = 0; r < 4; ++r)
                        atomicAdd(&glds[i][s * 16 + grp * 4 + r], p[r]);
                }
            }
            #pragma unroll
            for (int n = 0; n < 4; ++n) Cg[n] = Cn[n];
        }
    }
    __syncthreads();

    // ---- sigmoid + mask, gsum/deg reductions (to LDS)
    {
        const float bg2v = bg2[0];
        #pragma unroll
        for (int it = 0; it < NI / 2; ++it) {
            const int i = it * 2 + (t >> 7);
            const int j = t & 127;
            const float pre = glds[i][j] + bg2v;
            const float m = em[(size_t)(bi0 + i) * NN + j];
            const float g = m * __builtin_amdgcn_rcpf(1.0f + __expf(-pre));
            glds[i][j] = g;
            float gsv = g, dv = m;
            #pragma unroll
            for (int mm = 1; mm < 64; mm <<= 1) {
                gsv += __shfl_xor(gsv, mm, 64);
                dv  += __shfl_xor(dv, mm, 64);
            }
            if (lane == 0) { red[it][w][0] = gsv; red[it][w][1] = dv; }
        }
    }
    __syncthreads();
    if (t < NI) {
        const int it = t >> 1, w0 = (t & 1) * 2;
        gsumL[t] = red[it][w0][0] + red[it][w0 + 1][0];
        degL[t]  = red[it][w0][1] + red[it][w0 + 1][1];
    }

    // ================= msg pass
    float ts[NI][4];
    {
        float hmiR[NI][4];
        #pragma unroll
        for (int i = 0; i < NI; ++i)
            #pragma unroll
            for (int n = 0; n < 4; ++n)
                hmiR[i][n] = Hmi[(size_t)(bi0 + i) * ID + kcol + n * 16];
        #pragma unroll
        for (int i = 0; i < NI; ++i)
            #pragma unroll
            for (int n = 0; n < 4; ++n) ts[i][n] = 0.f;
        f32x4 Cm[4], Cn[4];
        #pragma unroll
        for (int n = 0; n < 4; ++n) Cm[n] = *(const f32x4*)(HmjL + n * 256);
        for (int s = 0; s < 8; ++s) {
            if (s < 7) {
                const float* ps = HmjL + (s + 1) * (ID * 16);
                #pragma unroll
                for (int n = 0; n < 4; ++n) Cn[n] = *(const f32x4*)(ps + n * 256);
            }
            #pragma unroll
            for (int i = 0; i < NI; ++i) {
                sh8 Af = *(const sh8*)&Elds[i * 4096 + s * 512 + lane * 8];
                f32x4 acc[4];
                #pragma unroll
                for (int n = 0; n < 4; ++n)
                    acc[n] = __builtin_amdgcn_mfma_f32_16x16x32_bf16(
                        Af, Bm[n], Cm[n], 0, 0, 0);
                f32x4 gr = *(const f32x4*)&glds[i][s * 16 + grp * 4];
                #pragma unroll
                for (int n = 0; n < 4; ++n)
                    #pragma unroll
                    for (int r = 0; r < 4; ++r)
                        ts[i][n] = fmaf(gr[r], ftanh(acc[n][r] + hmiR[i][n]),
                                        ts[i][n]);
            }
            #pragma unroll
            for (int n = 0; n < 4; ++n) Cm[n] = Cn[n];
        }
        #pragma unroll
        for (int i = 0; i < NI; ++i)
            #pragma unroll
            for (int n = 0; n < 4; ++n) {
                ts[i][n] += __shfl_xor(ts[i][n], 16, 64);
                ts[i][n] += __shfl_xor(ts[i][n], 32, 64);
            }
    }

    // ================= fused k34 tail (reuse Elds as f32 scratch)
    __syncthreads();                      // all Elds reads done
    float* scratch = (float*)Elds;
    float* Tl  = scratch;                 // [4][256]
    float* up  = scratch + 1024;          // [4][257]
    float* uu  = scratch + 2052;          // [4][256]
    float* xsb = scratch + 3076;          // [4][128]
    if (lane < 16) {
        #pragma unroll
        for (int i = 0; i < NI; ++i)
            #pragma unroll
            for (int n = 0; n < 4; ++n)
                Tl[i * 256 + w * 64 + n * 16 + lane] = ts[i][n];
    }
    #pragma unroll
    for (int it = 0; it < 2; ++it) {
        const int idx = it * 256 + t;
        const int i = idx >> 7, c = idx & 127;
        up[i * 257 + c] = h[(size_t)(bi0 + i) * SD + c];
    }
    if (t < NI) up[t * 257 + 2 * SD] = degL[t] * (1.0f / 127.0f);
    __syncthreads();
    {   // agg: up[i][128+d] = (T@Wm2 + g*bm2) / max(g,1)
        const int d = t & 127;
        const int r0 = (t >> 7) * 2;
        float acc0 = 0.f, acc1 = 0.f;
        for (int kk = 0; kk < ID; ++kk) {
            const float wv = Wm2[kk * SD + d];
            acc0 = fmaf(Tl[r0 * 256 + kk], wv, acc0);
            acc1 = fmaf(Tl[(r0 + 1) * 256 + kk], wv, acc1);
        }
        const float bmv = bm2[d];
        const float g0 = gsumL[r0], g1 = gsumL[r0 + 1];
        up[r0 * 257 + SD + d] = fmaf(g0, bmv, acc0) *
                                __builtin_amdgcn_rcpf(fmaxf(g0, 1.0f));
        up[(r0 + 1) * 257 + SD + d] = fmaf(g1, bmv, acc1) *
                                      __builtin_amdgcn_rcpf(fmaxf(g1, 1.0f));
    }
    __syncthreads();
    {   // FC1 (257 -> 256) + tanh
        float acc[NI];
        const float bk = bu1[t];
        #pragma unroll
        for (int i = 0; i < NI; ++i) acc[i] = bk;
        for (int c = 0; c < 2 * SD + 1; ++c) {
            const float wv = Wu1[c * ID + t];
            #pragma unroll
            for (int i = 0; i < NI; ++i)
                acc[i] = fmaf(up[i * 257 + c], wv, acc[i]);
        }
        #pragma unroll
        for (int i = 0; i < NI; ++i) uu[i * 256 + t] = ftanh(acc[i]);
    }
    __syncthreads();
    {   // FC2 (256 -> 128) + tanh + residual
        const int d = t & 127;
        const int r0 = (t >> 7) * 2;
        float acc0 = bu2[d], acc1 = acc0;
        for (int kk = 0; kk < ID; ++kk) {
            const float wv = Wu2[kk * SD + d];
            acc0 = fmaf(uu[r0 * 256 + kk], wv, acc0);
            acc1 = fmaf(uu[(r0 + 1) * 256 + kk], wv, acc1);
        }
        xsb[r0 * 128 + d] = up[r0 * 257 + d] + ftanh(acc0);
        xsb[(r0 + 1) * 128 + d] = up[(r0 + 1) * 257 + d] + ftanh(acc1);
    }
    __syncthreads();
    {   // LayerNorm: wave w -> row w
        const float v0 = xsb[w * 128 + lane], v1 = xsb[w * 128 + lane + 64];
        float s = v0 + v1;
        #pragma unroll
        for (int m = 1; m < 64; m <<= 1) s += __shfl_xor(s, m, 64);
        const float mu = s * (1.0f / SD);
        const float d0 = v0 - mu, d1 = v1 - mu;
        float q = d0 * d0 + d1 * d1;
        #pragma unroll
        for (int m = 1; m < 64; m <<= 1) q += __shfl_xor(q, m, 64);
        const float inv = rsqrtf(q * (1.0f / SD) + 1e-5f);
        out[(size_t)(bi0 + w) * SD + lane] = d0 * inv * lnw[lane] + lnb[lane];
        out[(size_t)(bi0 + w) * SD + lane + 64] =
            d1 * inv * lnw[lane + 64] + lnb[lane + 64];
    }
}

extern "C" void kernel_launch(void* const* d_in, const int* in_sizes, int n_in,
                              void* d_out, int out_size, void* d_ws, size_t ws_size,
                              hipStream_t stream) {
    const float* h   = (const float*)d_in[0];
    const float* ef  = (const float*)d_in[1];
    const float* em  = (const float*)d_in[2];
    const float* Wm1 = (const float*)d_in[3];
    const float* bm1 = (const float*)d_in[4];
    const float* Wm2 = (const float*)d_in[5];
    const float* bm2 = (const float*)d_in[6];
    const float* Wg1 = (const float*)d_in[7];
    const float* bg1 = (const float*)d_in[8];
    const float* Wg2 = (const float*)d_in[9];
    const float* bg2 = (const float*)d_in[10];
    const float* Wu1 = (const float*)d_in[11];
    const float* bu1 = (const float*)d_in[12];
    const float* Wu2 = (const float*)d_in[13];
    const float* bu2 = (const float*)d_in[14];
    const float* lnw = (const float*)d_in[15];
    const float* lnb = (const float*)d_in[16];

    float* ws = (float*)d_ws;
    float* Hgi   = ws;
    float* Hgjt  = Hgi + (size_t)BN * ID;
    float* Hmi   = Hgjt + (size_t)BN * ID;
    float* Hmjt  = Hmi + (size_t)BN * ID;
    ushort* Bprep = (ushort*)(Hmjt + (size_t)BN * ID);
    float* outp = (float*)d_out;

    k_prep<<<288, 64, 0, stream>>>(Wg1, Wm1, Bprep);
    k1_mfma<<<dim3(BN / 16, 4), 256, 0, stream>>>(h, bg1, bm1, Bprep,
                                                  Hgi, Hgjt, Hmi, Hmjt);
    k2_fused<<<BN / NI, 256, 0, stream>>>(ef, em, Bprep, Hgi, Hmi, Hgjt, Hmjt,
                                          Wg2, bg2, h, Wm2, bm2,
                                          Wu1, bu1, Wu2, bu2, lnw, lnb, outp);
}

// Round 11
// 119.820 us; speedup vs baseline: 1.6251x; 1.1780x over previous
//
#include <hip/hip_runtime.h>
#include <hip/hip_bf16.h>

#define BB 32
#define NN 128
#define SD 128
#define ED 32
#define ID 256
#define BN (BB*NN)   // 4096
#define NI 4         // i-blocks per k2 workgroup

// Bprep tile index bases
#define WM2B 288
#define WU1B 352
#define WU2B 480

typedef __attribute__((ext_vector_type(8))) short sh8;
typedef __attribute__((ext_vector_type(4))) float f32x4;

__device__ __forceinline__ float ftanh(float x) {
    float e2 = __expf(2.0f * x);
    return 1.0f - 2.0f * __builtin_amdgcn_rcpf(e2 + 1.0f);
}

__device__ __forceinline__ ushort f2bf(float f) {
    unsigned u = __float_as_uint(f);
    return (ushort)((u + 0x7FFF + ((u >> 16) & 1)) >> 16);
}

// build a bf16 A-frag (rows 0..3 real, 4..15 zero) from f32 LDS rows
__device__ __forceinline__ sh8 afragT(const float* base, int stride, int kt, int lane) {
    sh8 v = (sh8){0, 0, 0, 0, 0, 0, 0, 0};
    if ((lane & 15) < 4) {
        const float* p = base + (lane & 15) * stride + kt * 32 + (lane >> 4) * 8;
        f32x4 a0 = *(const f32x4*)p;
        f32x4 a1 = *(const f32x4*)(p + 4);
        v[0] = (short)f2bf(a0[0]); v[1] = (short)f2bf(a0[1]);
        v[2] = (short)f2bf(a0[2]); v[3] = (short)f2bf(a0[3]);
        v[4] = (short)f2bf(a1[0]); v[5] = (short)f2bf(a1[1]);
        v[6] = (short)f2bf(a1[2]); v[7] = (short)f2bf(a1[3]);
    }
    return v;
}

// ---------------------------------------------------------------------------
// k_prep: frag-ordered bf16 B-tiles.
// 0..255:   W1 h-parts [tgt(4)][kt(4)][nt(16)]
// 256..287: We rows 256..288 of W1 (16 gate + 16 msg)
// 288..351: Wm2 [kt(8)][nt(8)]     352..479: Wu1 rows 0..255 [kt(8)][nt(16)]
// 480..543: Wu2 [kt(8)][nt(8)]
// lane l: B[k = rowbase+(l>>4)*8+e][col = nt*16+(l&15)]
// grid 544, block 64
// ---------------------------------------------------------------------------
__global__ void k_prep(const float* __restrict__ Wg1, const float* __restrict__ Wm1,
                       const float* __restrict__ Wm2, const float* __restrict__ Wu1,
                       const float* __restrict__ Wu2, ushort* __restrict__ Bprep) {
    const int tt = blockIdx.x;
    const int l = threadIdx.x;
    const float* W;
    int rowbase, nt, stride;
    if (tt < 256) {
        const int tgt = tt >> 6;
        const int kt = (tt >> 4) & 3;
        nt = tt & 15;
        W = (tgt >= 2) ? Wm1 : Wg1;
        rowbase = (tgt & 1) * 128 + kt * 32;
        stride = ID;
    } else if (tt < WM2B) {
        const int wt = tt - 256;
        W = (wt >> 4) ? Wm1 : Wg1;
        rowbase = 2 * SD;
        nt = wt & 15;
        stride = ID;
    } else if (tt < WU1B) {
        const int wt = tt - WM2B;
        W = Wm2; rowbase = (wt >> 3) * 32; nt = wt & 7; stride = SD;
    } else if (tt < WU2B) {
        const int wt = tt - WU1B;
        W = Wu1; rowbase = (wt >> 4) * 32; nt = wt & 15; stride = ID;
    } else {
        const int wt = tt - WU2B;
        W = Wu2; rowbase = (wt >> 3) * 32; nt = wt & 7; stride = SD;
    }
    const int colw = nt * 16 + (l & 15);
    const int kb = rowbase + (l >> 4) * 8;
    sh8 v;
    #pragma unroll
    for (int e = 0; e < 8; ++e)
        v[e] = (short)f2bf(W[(size_t)(kb + e) * stride + colw]);
    *(sh8*)&Bprep[(size_t)tt * 512 + l * 8] = v;
}

// ---------------------------------------------------------------------------
// K1 (MFMA): one 16-row stripe x one target per block (grid.y = tgt).
// grid (BN/16, 4), block 256
// ---------------------------------------------------------------------------
__global__ __launch_bounds__(256) void k1_mfma(
        const float* __restrict__ h,
        const float* __restrict__ bg1, const float* __restrict__ bm1,
        const ushort* __restrict__ Bprep,
        float* __restrict__ Hgi, float* __restrict__ Hgjt,
        float* __restrict__ Hmi, float* __restrict__ Hmjt) {
    const int blk = blockIdx.x;
    const int tgt = blockIdx.y;
    const int t = threadIdx.x;
    const int w = t >> 6;
    const int lane = t & 63;
    const int col = lane & 15;
    const int grp = lane >> 4;
    __shared__ __align__(16) ushort Alds[4 * 512];

    {   // stage h rows -> bf16 frag order
        const int c = t;
        const int kt = c >> 6, l = c & 63;
        const int row = l & 15;
        const int kb = kt * 32 + (l >> 4) * 8;
        const float* p = h + (size_t)(blk * 16 + row) * SD + kb;
        f32x4 a0 = *(const f32x4*)p;
        f32x4 a1 = *(const f32x4*)(p + 4);
        sh8 v;
        v[0] = (short)f2bf(a0[0]); v[1] = (short)f2bf(a0[1]);
        v[2] = (short)f2bf(a0[2]); v[3] = (short)f2bf(a0[3]);
        v[4] = (short)f2bf(a1[0]); v[5] = (short)f2bf(a1[1]);
        v[6] = (short)f2bf(a1[2]); v[7] = (short)f2bf(a1[3]);
        *(sh8*)&Alds[c * 8] = v;
    }
    __syncthreads();

    const int kcol = w * 64 + col;
    sh8 Af[4];
    #pragma unroll
    for (int kt = 0; kt < 4; ++kt)
        Af[kt] = *(const sh8*)&Alds[kt * 512 + lane * 8];

    f32x4 acc[4];
    #pragma unroll
    for (int n = 0; n < 4; ++n) acc[n] = (f32x4){0.f, 0.f, 0.f, 0.f};
    #pragma unroll
    for (int kt = 0; kt < 4; ++kt)
        #pragma unroll
        for (int n = 0; n < 4; ++n) {
            sh8 Bf = *(const sh8*)&Bprep[
                (size_t)(tgt * 64 + kt * 16 + w * 4 + n) * 512 + lane * 8];
            acc[n] = __builtin_amdgcn_mfma_f32_16x16x32_bf16(
                Af[kt], Bf, acc[n], 0, 0, 0);
        }
    if (tgt & 1) {
        float* out = (tgt == 1) ? Hgjt : Hmjt;
        #pragma unroll
        for (int n = 0; n < 4; ++n)
            *(f32x4*)&out[((size_t)blk * ID + kcol + n * 16) * 16 + grp * 4] = acc[n];
    } else {
        const float* bias = (tgt == 0) ? bg1 : bm1;
        float* out = (tgt == 0) ? Hgi : Hmi;
        #pragma unroll
        for (int n = 0; n < 4; ++n) {
            const float bv = bias[kcol + n * 16];
            #pragma unroll
            for (int r = 0; r < 4; ++r)
                out[(size_t)(blk * 16 + grp * 4 + r) * ID + kcol + n * 16] =
                    acc[n][r] + bv;
        }
    }
}

// ---------------------------------------------------------------------------
// K2 fused: edge passes (R5 form) + MFMA tail (agg/FC1/FC2 as M=16 bf16
// MFMAs with 4 live rows) + residual + LayerNorm. grid BN/NI, block 256
// ---------------------------------------------------------------------------
__global__ __launch_bounds__(256, 4) void k2_fused(
        const float* __restrict__ ef, const float* __restrict__ em,
        const ushort* __restrict__ Bprep,
        const float* __restrict__ Hgi, const float* __restrict__ Hmi,
        const float* __restrict__ Hgjt, const float* __restrict__ Hmjt,
        const float* __restrict__ Wg2, const float* __restrict__ bg2,
        const float* __restrict__ h,
        const float* __restrict__ Wu1, const float* __restrict__ bu1,
        const float* __restrict__ bu2, const float* __restrict__ bm2,
        const float* __restrict__ lnw, const float* __restrict__ lnb,
        float* __restrict__ out) {
    const int bi0 = blockIdx.x * NI;
    const int b = bi0 >> 7;
    const int t = threadIdx.x;
    const int w = t >> 6;
    const int lane = t & 63;
    const int col = lane & 15;
    const int grp = lane >> 4;

    __shared__ __align__(16) ushort Elds[NI * 8 * 512];   // 32 KB
    __shared__ float glds[NI][NN];                        // 2 KB
    __shared__ float red[2][4][2];
    __shared__ float gsumL[NI], degL[NI];

    {
        float* gl = &glds[0][0];
        gl[t] = 0.f;
        gl[t + 256] = 0.f;
    }
    #pragma unroll
    for (int i = 0; i < NI; ++i) {
        const float* efb = ef + (size_t)(bi0 + i) * NN * ED;
        #pragma unroll
        for (int it = 0; it < 2; ++it) {
            const int c = it * 256 + t;
            const int j = ((c >> 6) << 4) | (c & 15);
            const int kb = ((c >> 4) & 3) * 8;
            const float* p = efb + j * ED + kb;
            f32x4 a0 = *(const f32x4*)p;
            f32x4 a1 = *(const f32x4*)(p + 4);
            sh8 v;
            v[0] = (short)f2bf(a0[0]); v[1] = (short)f2bf(a0[1]);
            v[2] = (short)f2bf(a0[2]); v[3] = (short)f2bf(a0[3]);
            v[4] = (short)f2bf(a1[0]); v[5] = (short)f2bf(a1[1]);
            v[6] = (short)f2bf(a1[2]); v[7] = (short)f2bf(a1[3]);
            *(sh8*)&Elds[i * 4096 + c * 8] = v;
        }
    }
    __syncthreads();

    const int kcol = w * 64 + col;
    sh8 Bg[4], Bm[4];
    #pragma unroll
    for (int n = 0; n < 4; ++n) {
        Bg[n] = *(const sh8*)&Bprep[(size_t)(256 + w * 4 + n) * 512 + lane * 8];
        Bm[n] = *(const sh8*)&Bprep[(size_t)(272 + w * 4 + n) * 512 + lane * 8];
    }
    const float* HgjL = Hgjt + (size_t)b * 8 * ID * 16 + (size_t)kcol * 16 + grp * 4;
    const float* HmjL = Hmjt + (size_t)b * 8 * ID * 16 + (size_t)kcol * 16 + grp * 4;

    // ================= gate pass
    {
        float hgiR[NI][4], wg2R[4];
        #pragma unroll
        for (int n = 0; n < 4; ++n) wg2R[n] = Wg2[kcol + n * 16];
        #pragma unroll
        for (int i = 0; i < NI; ++i)
            #pragma unroll
            for (int n = 0; n < 4; ++n)
                hgiR[i][n] = Hgi[(size_t)(bi0 + i) * ID + kcol + n * 16];
        f32x4 Cg[4], Cn[4];
        #pragma unroll
        for (int n = 0; n < 4; ++n) Cg[n] = *(const f32x4*)(HgjL + n * 256);
        for (int s = 0; s < 8; ++s) {
            if (s < 7) {
                const float* ps = HgjL + (s + 1) * (ID * 16);
                #pragma unroll
                for (int n = 0; n < 4; ++n) Cn[n] = *(const f32x4*)(ps + n * 256);
            }
            #pragma unroll
            for (int i = 0; i < NI; ++i) {
                sh8 Af = *(const sh8*)&Elds[i * 4096 + s * 512 + lane * 8];
                f32x4 acc[4];
                #pragma unroll
                for (int n = 0; n < 4; ++n)
                    acc[n] = __builtin_amdgcn_mfma_f32_16x16x32_bf16(
                        Af, Bg[n], Cg[n], 0, 0, 0);
                float p[4] = {0.f, 0.f, 0.f, 0.f};
                #pragma unroll
                for (int n = 0; n < 4; ++n)
                    #pragma unroll
                    for (int r = 0; r < 4; ++r)
                        p[r] = fmaf(ftanh(acc[n][r] + hgiR[i][n]), wg2R[n], p[r]);
                #pragma unroll
                for (int m = 1; m < 16; m <<= 1)
                    #pragma unroll
                    for (int r = 0; r < 4; ++r) p[r] += __shfl_xor(p[r], m, 64);
                if (col == 0) {
                    #pragma unroll
                    for (int r = 0; r < 4; ++r)
                        atomicAdd(&glds[i][s * 16 + grp * 4 + r], p[r]);
                }
            }
            #pragma unroll
            for (int n = 0; n < 4; ++n) Cg[n] = Cn[n];
        }
    }
    __syncthreads();

    // ---- sigmoid + mask, gsum/deg reductions (to LDS)
    {
        const float bg2v = bg2[0];
        #pragma unroll
        for (int it = 0; it < NI / 2; ++it) {
            const int i = it * 2 + (t >> 7);
            const int j = t & 127;
            const float pre = glds[i][j] + bg2v;
            const float m = em[(size_t)(bi0 + i) * NN + j];
            const float g = m * __builtin_amdgcn_rcpf(1.0f + __expf(-pre));
            glds[i][j] = g;
            float gsv = g, dv = m;
            #pragma unroll
            for (int mm = 1; mm < 64; mm <<= 1) {
                gsv += __shfl_xor(gsv, mm, 64);
                dv  += __shfl_xor(dv, mm, 64);
            }
            if (lane == 0) { red[it][w][0] = gsv; red[it][w][1] = dv; }
        }
    }
    __syncthreads();
    if (t < NI) {
        const int it = t >> 1, w0 = (t & 1) * 2;
        gsumL[t] = red[it][w0][0] + red[it][w0 + 1][0];
        degL[t]  = red[it][w0][1] + red[it][w0 + 1][1];
    }

    // ================= msg pass
    float ts[NI][4];
    {
        float hmiR[NI][4];
        #pragma unroll
        for (int i = 0; i < NI; ++i)
            #pragma unroll
            for (int n = 0; n < 4; ++n)
                hmiR[i][n] = Hmi[(size_t)(bi0 + i) * ID + kcol + n * 16];
        #pragma unroll
        for (int i = 0; i < NI; ++i)
            #pragma unroll
            for (int n = 0; n < 4; ++n) ts[i][n] = 0.f;
        f32x4 Cm[4], Cn[4];
        #pragma unroll
        for (int n = 0; n < 4; ++n) Cm[n] = *(const f32x4*)(HmjL + n * 256);
        for (int s = 0; s < 8; ++s) {
            if (s < 7) {
                const float* ps = HmjL + (s + 1) * (ID * 16);
                #pragma unroll
                for (int n = 0; n < 4; ++n) Cn[n] = *(const f32x4*)(ps + n * 256);
            }
            #pragma unroll
            for (int i = 0; i < NI; ++i) {
                sh8 Af = *(const sh8*)&Elds[i * 4096 + s * 512 + lane * 8];
                f32x4 acc[4];
                #pragma unroll
                for (int n = 0; n < 4; ++n)
                    acc[n] = __builtin_amdgcn_mfma_f32_16x16x32_bf16(
                        Af, Bm[n], Cm[n], 0, 0, 0);
                f32x4 gr = *(const f32x4*)&glds[i][s * 16 + grp * 4];
                #pragma unroll
                for (int n = 0; n < 4; ++n)
                    #pragma unroll
                    for (int r = 0; r < 4; ++r)
                        ts[i][n] = fmaf(gr[r], ftanh(acc[n][r] + hmiR[i][n]),
                                        ts[i][n]);
            }
            #pragma unroll
            for (int n = 0; n < 4; ++n) Cm[n] = Cn[n];
        }
        #pragma unroll
        for (int i = 0; i < NI; ++i)
            #pragma unroll
            for (int n = 0; n < 4; ++n) {
                ts[i][n] += __shfl_xor(ts[i][n], 16, 64);
                ts[i][n] += __shfl_xor(ts[i][n], 32, 64);
            }
    }

    // ================= MFMA tail (reuse Elds as f32 scratch)
    __syncthreads();                      // all Elds/glds reads done
    float* scratch = (float*)Elds;
    float* Tl  = scratch;                 // [4][256]
    float* up  = scratch + 1024;          // [4][260] (stride 260 -> 16B-aligned rows)
    float* uu  = scratch + 2064;          // [4][256]
    float* xsb = scratch + 3088;          // [4][128]
    if (lane < 16) {
        #pragma unroll
        for (int i = 0; i < NI; ++i)
            #pragma unroll
            for (int n = 0; n < 4; ++n)
                Tl[i * 256 + w * 64 + n * 16 + lane] = ts[i][n];
    }
    #pragma unroll
    for (int it = 0; it < 2; ++it) {
        const int idx = it * 256 + t;
        const int i = idx >> 7, c = idx & 127;
        up[i * 260 + c] = h[(size_t)(bi0 + i) * SD + c];
    }
    if (t < NI) up[t * 260 + 256] = degL[t] * (1.0f / 127.0f);
    __syncthreads();

    {   // agg: up[i][128+d] = (T@Wm2 + g*bm2)/max(g,1); wave w -> nt {2w,2w+1}
        f32x4 acc[2];
        acc[0] = (f32x4){0.f, 0.f, 0.f, 0.f};
        acc[1] = (f32x4){0.f, 0.f, 0.f, 0.f};
        #pragma unroll
        for (int kt = 0; kt < 8; ++kt) {
            sh8 Af = afragT(Tl, 256, kt, lane);
            #pragma unroll
            for (int n2 = 0; n2 < 2; ++n2) {
                sh8 Bf = *(const sh8*)&Bprep[
                    (size_t)(WM2B + kt * 8 + w * 2 + n2) * 512 + lane * 8];
                acc[n2] = __builtin_amdgcn_mfma_f32_16x16x32_bf16(Af, Bf, acc[n2], 0, 0, 0);
            }
        }
        if (grp == 0) {
            #pragma unroll
            for (int n2 = 0; n2 < 2; ++n2) {
                const int d = (w * 2 + n2) * 16 + lane;
                const float bmv = bm2[d];
                #pragma unroll
                for (int r = 0; r < 4; ++r) {
                    const float g = gsumL[r];
                    up[r * 260 + SD + d] = fmaf(g, bmv, acc[n2][r]) *
                                           __builtin_amdgcn_rcpf(fmaxf(g, 1.0f));
                }
            }
        }
    }
    __syncthreads();

    {   // FC1: uu = tanh(up@Wu1 + bu1 + deg-row); wave w -> nt {4w..4w+3}
        f32x4 acc[4];
        #pragma unroll
        for (int n2 = 0; n2 < 4; ++n2) acc[n2] = (f32x4){0.f, 0.f, 0.f, 0.f};
        #pragma unroll
        for (int kt = 0; kt < 8; ++kt) {
            sh8 Af = afragT(up, 260, kt, lane);
            #pragma unroll
            for (int n2 = 0; n2 < 4; ++n2) {
                sh8 Bf = *(const sh8*)&Bprep[
                    (size_t)(WU1B + kt * 16 + w * 4 + n2) * 512 + lane * 8];
                acc[n2] = __builtin_amdgcn_mfma_f32_16x16x32_bf16(Af, Bf, acc[n2], 0, 0, 0);
            }
        }
        if (grp == 0) {
            #pragma unroll
            for (int n2 = 0; n2 < 4; ++n2) {
                const int kc = (w * 4 + n2) * 16 + lane;
                const float wdeg = Wu1[(size_t)(2 * SD) * ID + kc];
                const float bb = bu1[kc];
                #pragma unroll
                for (int r = 0; r < 4; ++r)
                    uu[r * 256 + kc] =
                        ftanh(acc[n2][r] + bb + up[r * 260 + 256] * wdeg);
            }
        }
    }
    __syncthreads();

    {   // FC2 + residual: xs = h + tanh(uu@Wu2 + bu2); wave w -> nt {2w,2w+1}
        f32x4 acc[2];
        acc[0] = (f32x4){0.f, 0.f, 0.f, 0.f};
        acc[1] = (f32x4){0.f, 0.f, 0.f, 0.f};
        #pragma unroll
        for (int kt = 0; kt < 8; ++kt) {
            sh8 Af = afragT(uu, 256, kt, lane);
            #pragma unroll
            for (int n2 = 0; n2 < 2; ++n2) {
                sh8 Bf = *(const sh8*)&Bprep[
                    (size_t)(WU2B + kt * 8 + w * 2 + n2) * 512 + lane * 8];
                acc[n2] = __builtin_amdgcn_mfma_f32_16x16x32_bf16(Af, Bf, acc[n2], 0, 0, 0);
            }
        }
        if (grp == 0) {
            #pragma unroll
            for (int n2 = 0; n2 < 2; ++n2) {
                const int d = (w * 2 + n2) * 16 + lane;
                const float bb = bu2[d];
                #pragma unroll
                for (int r = 0; r < 4; ++r)
                    xsb[r * 128 + d] = up[r * 260 + d] + ftanh(acc[n2][r] + bb);
            }
        }
    }
    __syncthreads();

    {   // LayerNorm: wave w -> row w
        const float v0 = xsb[w * 128 + lane], v1 = xsb[w * 128 + lane + 64];
        float s = v0 + v1;
        #pragma unroll
        for (int m = 1; m < 64; m <<= 1) s += __shfl_xor(s, m, 64);
        const float mu = s * (1.0f / SD);
        const float d0 = v0 - mu, d1 = v1 - mu;
        float q = d0 * d0 + d1 * d1;
        #pragma unroll
        for (int m = 1; m < 64; m <<= 1) q += __shfl_xor(q, m, 64);
        const float inv = rsqrtf(q * (1.0f / SD) + 1e-5f);
        out[(size_t)(bi0 + w) * SD + lane] = d0 * inv * lnw[lane] + lnb[lane];
        out[(size_t)(bi0 + w) * SD + lane + 64] =
            d1 * inv * lnw[lane + 64] + lnb[lane + 64];
    }
}

extern "C" void kernel_launch(void* const* d_in, const int* in_sizes, int n_in,
                              void* d_out, int out_size, void* d_ws, size_t ws_size,
                              hipStream_t stream) {
    const float* h   = (const float*)d_in[0];
    const float* ef  = (const float*)d_in[1];
    const float* em  = (const float*)d_in[2];
    const float* Wm1 = (const float*)d_in[3];
    const float* bm1 = (const float*)d_in[4];
    const float* Wm2 = (const float*)d_in[5];
    const float* bm2 = (const float*)d_in[6];
    const float* Wg1 = (const float*)d_in[7];
    const float* bg1 = (const float*)d_in[8];
    const float* Wg2 = (const float*)d_in[9];
    const float* bg2 = (const float*)d_in[10];
    const float* Wu1 = (const float*)d_in[11];
    const float* bu1 = (const float*)d_in[12];
    const float* Wu2 = (const float*)d_in[13];
    const float* bu2 = (const float*)d_in[14];
    const float* lnw = (const float*)d_in[15];
    const float* lnb = (const float*)d_in[16];

    float* ws = (float*)d_ws;
    float* Hgi   = ws;
    float* Hgjt  = Hgi + (size_t)BN * ID;
    float* Hmi   = Hgjt + (size_t)BN * ID;
    float* Hmjt  = Hmi + (size_t)BN * ID;
    ushort* Bprep = (ushort*)(Hmjt + (size_t)BN * ID);
    float* outp = (float*)d_out;

    k_prep<<<544, 64, 0, stream>>>(Wg1, Wm1, Wm2, Wu1, Wu2, Bprep);
    k1_mfma<<<dim3(BN / 16, 4), 256, 0, stream>>>(h, bg1, bm1, Bprep,
                                                  Hgi, Hgjt, Hmi, Hmjt);
    k2_fused<<<BN / NI, 256, 0, stream>>>(ef, em, Bprep, Hgi, Hmi, Hgjt, Hmjt,
                                          Wg2, bg2, h, Wu1, bu1, bu2, bm2,
                                          lnw, lnb, outp);
}